// Round 3
// baseline (495.358 us; speedup 1.0000x reference)
//
#include <hip/hip_runtime.h>
#include <hip/hip_bf16.h>
#include <math.h>

#define NCLS 40
#define BW 32          // nodes per bucket
#define BSH 5          // log2(BW)
#define PKSH 26        // dstLocal packed at bits 26..30

typedef __attribute__((ext_vector_type(8))) short bf16x8;
typedef __attribute__((ext_vector_type(4))) float f32x4;

__device__ inline float bf2f(ushort u) {
    unsigned v = ((unsigned)u) << 16;
    float f;
    __builtin_memcpy(&f, &v, 4);
    return f;
}
__device__ inline ushort f2bf(float f) {
    unsigned v;
    __builtin_memcpy(&v, &f, 4);
    unsigned r = (v + 0x7FFFu + ((v >> 16) & 1u)) >> 16;
    return (ushort)r;
}

// ---------------------------------------------------------------------------
// convW1: W1 [512][64] fp32 -> W1t [64][512] bf16 (transposed)
// ---------------------------------------------------------------------------
__global__ __launch_bounds__(256) void convW1_kernel(const float* __restrict__ W1,
                                                     ushort* __restrict__ W1t)
{
    int id = blockIdx.x * 256 + threadIdx.x;  // 32768
    if (id >= 512 * 64) return;
    int k = id >> 6, c = id & 63;
    W1t[c * 512 + k] = f2bf(W1[k * 64 + c]);
}

// ---------------------------------------------------------------------------
// GEMM1 (MFMA): h1b = bf16(x) @ bf16(W1). 64-row tile, 256 thr = 4 waves.
// ---------------------------------------------------------------------------
__global__ __launch_bounds__(256) void gemm1_mfma_kernel(
    const float* __restrict__ x, const ushort* __restrict__ W1t,
    ushort* __restrict__ h1b, int Nn)
{
    __shared__ ushort As[64 * 40];
    __shared__ ushort Bs[64 * 40];
    const int t = threadIdx.x;
    const int lane = t & 63, w = t >> 6;
    const int tile = blockIdx.x * 64;

    f32x4 acc[4] = {};

    const int sr = t >> 2;
    const int sk = (t & 3) * 8;
    const int arow = tile + sr;
    const bool rowok = arow < Nn;
    const float* xrow = x + (size_t)arow * 512;
    const ushort* wrow = W1t + (size_t)sr * 512;

    const int r = lane & 15, g = lane >> 4;

    for (int k0 = 0; k0 < 512; k0 += 32) {
        float4 f0, f1;
        if (rowok) {
            f0 = *(const float4*)(xrow + k0 + sk);
            f1 = *(const float4*)(xrow + k0 + sk + 4);
        } else {
            f0 = make_float4(0.f, 0.f, 0.f, 0.f);
            f1 = f0;
        }
        ushort* ap = &As[sr * 40 + sk];
        ap[0] = f2bf(f0.x); ap[1] = f2bf(f0.y); ap[2] = f2bf(f0.z); ap[3] = f2bf(f0.w);
        ap[4] = f2bf(f1.x); ap[5] = f2bf(f1.y); ap[6] = f2bf(f1.z); ap[7] = f2bf(f1.w);
        *(bf16x8*)&Bs[sr * 40 + sk] = *(const bf16x8*)(wrow + k0 + sk);
        __syncthreads();

        bf16x8 afrag = *(const bf16x8*)&As[(w * 16 + r) * 40 + g * 8];
#pragma unroll
        for (int cb = 0; cb < 4; cb++) {
            bf16x8 bfrag = *(const bf16x8*)&Bs[(cb * 16 + r) * 40 + g * 8];
            acc[cb] = __builtin_amdgcn_mfma_f32_16x16x32_bf16(afrag, bfrag, acc[cb], 0, 0, 0);
        }
        __syncthreads();
    }

#pragma unroll
    for (int cb = 0; cb < 4; cb++) {
#pragma unroll
        for (int v = 0; v < 4; v++) {
            int row = tile + w * 16 + g * 4 + v;
            if (row < Nn) h1b[(size_t)row * 64 + cb * 16 + r] = f2bf(acc[cb][v]);
        }
    }
}

// ---------------------------------------------------------------------------
// elr1: el1[n,h] = sum_d h1[n,h,d]*al1[h,d]; er1 likewise. thread = n*8+h.
// ---------------------------------------------------------------------------
__global__ __launch_bounds__(256) void elr1_kernel(
    const ushort* __restrict__ h1b, const float* __restrict__ al1,
    const float* __restrict__ ar1, float* __restrict__ el1,
    float* __restrict__ er1, int Nn)
{
    int id = blockIdx.x * 256 + threadIdx.x;
    if (id >= Nn * 8) return;
    int h = id & 7;
    const ushort* p = h1b + (size_t)id * 8;
    ushort4 u0 = *(const ushort4*)p;
    ushort4 u1 = *(const ushort4*)(p + 4);
    float v0 = bf2f(u0.x), v1 = bf2f(u0.y), v2 = bf2f(u0.z), v3 = bf2f(u0.w);
    float v4 = bf2f(u1.x), v5 = bf2f(u1.y), v6 = bf2f(u1.z), v7 = bf2f(u1.w);
    const float* a = al1 + h * 8;
    const float* b = ar1 + h * 8;
    el1[id] = v0 * a[0] + v1 * a[1] + v2 * a[2] + v3 * a[3] + v4 * a[4] + v5 * a[5] + v6 * a[6] + v7 * a[7];
    er1[id] = v0 * b[0] + v1 * b[1] + v2 * b[2] + v3 * b[3] + v4 * b[4] + v5 * b[5] + v6 * b[6] + v7 * b[7];
}

// ---------------------------------------------------------------------------
// CSR build: count, 2-level scan, bucketed 2-phase scatter
// ---------------------------------------------------------------------------
__global__ __launch_bounds__(256) void count_kernel(const int* __restrict__ dst,
                                                    int* __restrict__ counts, int Ee)
{
    int i = blockIdx.x * blockDim.x + threadIdx.x;
    if (i < Ee) atomicAdd(&counts[dst[i]], 1);
}

__global__ __launch_bounds__(256) void scan1_kernel(const int* __restrict__ counts,
                                                    int* __restrict__ row_start,
                                                    int* __restrict__ blockSums, int Nn)
{
    __shared__ int s[256];
    int tid = threadIdx.x;
    int i = blockIdx.x * 256 + tid;
    int v = (i < Nn) ? counts[i] : 0;
    s[tid] = v;
    __syncthreads();
#pragma unroll
    for (int o = 1; o < 256; o <<= 1) {
        int t = (tid >= o) ? s[tid - o] : 0;
        __syncthreads();
        s[tid] += t;
        __syncthreads();
    }
    if (i < Nn) row_start[i] = s[tid] - v;
    if (tid == 255) blockSums[blockIdx.x] = s[255];
}

__global__ __launch_bounds__(512) void scan2_kernel(int* __restrict__ blockSums, int nb)
{
    __shared__ int s[512];
    int tid = threadIdx.x;
    int v = (tid < nb) ? blockSums[tid] : 0;
    s[tid] = v;
    __syncthreads();
#pragma unroll
    for (int o = 1; o < 512; o <<= 1) {
        int t = (tid >= o) ? s[tid - o] : 0;
        __syncthreads();
        s[tid] += t;
        __syncthreads();
    }
    if (tid < nb) blockSums[tid] = s[tid] - v;
}

__global__ __launch_bounds__(256) void scan3_kernel(int* __restrict__ row_start,
                                                    const int* __restrict__ blockOffs,
                                                    int* __restrict__ row_cur, int Nn, int Ee)
{
    int i = blockIdx.x * blockDim.x + threadIdx.x;
    if (i < Nn) {
        int v = row_start[i] + blockOffs[i >> 8];
        row_start[i] = v;
        row_cur[i] = v;
    }
    if (i == 0) row_start[Nn] = Ee;
}

// bucket cursor init: bcur[b] = row_start[b*BW]
__global__ __launch_bounds__(256) void bcur_init_kernel(const int* __restrict__ row_start,
                                                        int* __restrict__ bcur, int nBuckets)
{
    int b = blockIdx.x * blockDim.x + threadIdx.x;
    if (b < nBuckets) bcur[b] = row_start[b << BSH];
}

// phase B: append packed (src | dstLocal<<PKSH) into bucket region
__global__ __launch_bounds__(256) void bucket_scatter_kernel(
    const int* __restrict__ src, const int* __restrict__ dst,
    int* __restrict__ bcur, unsigned* __restrict__ packed, int Ee)
{
    int i = blockIdx.x * blockDim.x + threadIdx.x;
    if (i < Ee) {
        int d = dst[i];
        int p = atomicAdd(&bcur[d >> BSH], 1);
        packed[p] = (unsigned)src[i] | ((unsigned)(d & (BW - 1)) << PKSH);
    }
}

// phase C: one workgroup per bucket; dense read, near-local scatter
__global__ __launch_bounds__(256) void final_scatter_kernel(
    const unsigned* __restrict__ packed, const int* __restrict__ row_start,
    int* __restrict__ row_cur, int* __restrict__ perm_src, int Nn, int Ee)
{
    int b = blockIdx.x;
    int base = b << BSH;
    int beg = row_start[base];
    int nxt = base + BW;
    int endv = (nxt >= Nn) ? Ee : row_start[nxt];
    for (int i = beg + threadIdx.x; i < endv; i += 256) {
        unsigned pk = packed[i];
        int d = base + (int)(pk >> PKSH);
        int p = atomicAdd(&row_cur[d], 1);
        perm_src[p] = (int)(pk & ((1u << PKSH) - 1u));
    }
}

// ---------------------------------------------------------------------------
// agg1: one wave per dst node, lane = h*8+d. Single pass (no max; |e| small).
// ---------------------------------------------------------------------------
__global__ __launch_bounds__(256) void agg1_kernel(
    const ushort* __restrict__ h1b, const float* __restrict__ el1,
    const float* __restrict__ er1, const int* __restrict__ row_start,
    const int* __restrict__ perm_src, const float* __restrict__ b1,
    ushort* __restrict__ hmidb, int Nn)
{
    int wid = (blockIdx.x * blockDim.x + threadIdx.x) >> 6;
    int lane = threadIdx.x & 63;
    if (wid >= Nn) return;
    const int h = lane >> 3;
    const int beg = row_start[wid], end = row_start[wid + 1];
    const float er = er1[wid * 8 + h];

    float acc = 0.f, denom = 0.f;
    for (int i0 = beg; i0 < end; i0 += 64) {
        int cnt = min(end - i0, 64);
        int pv = (i0 + lane < end) ? perm_src[i0 + lane] : 0;
        int j = 0;
        for (; j + 4 <= cnt; j += 4) {
            int s0 = __shfl(pv, j), s1 = __shfl(pv, j + 1);
            int s2 = __shfl(pv, j + 2), s3 = __shfl(pv, j + 3);
            float e0 = el1[s0 * 8 + h] + er;
            float e1 = el1[s1 * 8 + h] + er;
            float e2 = el1[s2 * 8 + h] + er;
            float e3 = el1[s3 * 8 + h] + er;
            ushort r0 = h1b[(size_t)s0 * 64 + lane];
            ushort r1 = h1b[(size_t)s1 * 64 + lane];
            ushort r2 = h1b[(size_t)s2 * 64 + lane];
            ushort r3 = h1b[(size_t)s3 * 64 + lane];
            e0 = (e0 >= 0.f) ? e0 : 0.2f * e0;
            e1 = (e1 >= 0.f) ? e1 : 0.2f * e1;
            e2 = (e2 >= 0.f) ? e2 : 0.2f * e2;
            e3 = (e3 >= 0.f) ? e3 : 0.2f * e3;
            float w0 = __expf(fminf(e0, 80.f)), w1 = __expf(fminf(e1, 80.f));
            float w2 = __expf(fminf(e2, 80.f)), w3 = __expf(fminf(e3, 80.f));
            denom += (w0 + w1) + (w2 + w3);
            acc += bf2f(r0) * w0 + bf2f(r1) * w1 + bf2f(r2) * w2 + bf2f(r3) * w3;
        }
        for (; j < cnt; j++) {
            int s = __shfl(pv, j);
            float e = el1[s * 8 + h] + er;
            e = (e >= 0.f) ? e : 0.2f * e;
            float w = __expf(fminf(e, 80.f));
            denom += w;
            acc += bf2f(h1b[(size_t)s * 64 + lane]) * w;
        }
    }
    float v = acc / (denom + 1e-9f) + b1[lane];
    v = (v > 0.f) ? v : expm1f(v);  // ELU
    hmidb[(size_t)wid * 64 + lane] = f2bf(v);
}

// ---------------------------------------------------------------------------
// prep2: wal2[k] = sum_c W2[k][c]*al2[c]; war2 likewise
// ---------------------------------------------------------------------------
__global__ __launch_bounds__(64) void prep2_kernel(const float* __restrict__ W2,
                                                   const float* __restrict__ al2,
                                                   const float* __restrict__ ar2,
                                                   float* __restrict__ wal2,
                                                   float* __restrict__ war2)
{
    int k = threadIdx.x;  // 64
    float a = 0.f, b = 0.f;
    for (int c = 0; c < NCLS; c++) {
        float w = W2[k * NCLS + c];
        a += w * al2[c];
        b += w * ar2[c];
    }
    wal2[k] = a;
    war2[k] = b;
}

// ---------------------------------------------------------------------------
// GEMM2: h2b = hmid @ W2 (bf16 in, bf16 out) + el2/er2. One thread per node.
// ---------------------------------------------------------------------------
__global__ __launch_bounds__(256) void gemm2_kernel(
    const ushort* __restrict__ hmidb, const float* __restrict__ W2,
    const float* __restrict__ wal2, const float* __restrict__ war2,
    ushort* __restrict__ h2b, float* __restrict__ el2, float* __restrict__ er2,
    int Nn)
{
    __shared__ float w2s[64 * NCLS];
    __shared__ float wals[64], wars[64];
    for (int i = threadIdx.x; i < 64 * NCLS; i += blockDim.x) w2s[i] = W2[i];
    if (threadIdx.x < 64) {
        wals[threadIdx.x] = wal2[threadIdx.x];
        wars[threadIdx.x] = war2[threadIdx.x];
    }
    __syncthreads();
    int n = blockIdx.x * blockDim.x + threadIdx.x;
    if (n >= Nn) return;

    float out[NCLS];
#pragma unroll
    for (int c = 0; c < NCLS; c++) out[c] = 0.f;
    float accel = 0.f, accer = 0.f;

#pragma unroll 4
    for (int k4 = 0; k4 < 16; k4++) {
        ushort4 u = *(const ushort4*)&hmidb[(size_t)n * 64 + k4 * 4];
        float h0 = bf2f(u.x), h1 = bf2f(u.y), h2 = bf2f(u.z), h3 = bf2f(u.w);
        accel += h0 * wals[k4 * 4] + h1 * wals[k4 * 4 + 1] + h2 * wals[k4 * 4 + 2] + h3 * wals[k4 * 4 + 3];
        accer += h0 * wars[k4 * 4] + h1 * wars[k4 * 4 + 1] + h2 * wars[k4 * 4 + 2] + h3 * wars[k4 * 4 + 3];
#pragma unroll
        for (int c = 0; c < NCLS; c++) {
            out[c] += h0 * w2s[(k4 * 4 + 0) * NCLS + c] + h1 * w2s[(k4 * 4 + 1) * NCLS + c] +
                      h2 * w2s[(k4 * 4 + 2) * NCLS + c] + h3 * w2s[(k4 * 4 + 3) * NCLS + c];
        }
    }
    el2[n] = accel;
    er2[n] = accer;
#pragma unroll
    for (int c = 0; c < NCLS; c++) h2b[(size_t)n * NCLS + c] = f2bf(out[c]);
}

// ---------------------------------------------------------------------------
// agg2 + log_softmax: one wave per dst node; lane = class. Single pass.
// ---------------------------------------------------------------------------
__global__ __launch_bounds__(256) void agg2_kernel(
    const ushort* __restrict__ h2b, const float* __restrict__ el2,
    const float* __restrict__ er2, const int* __restrict__ row_start,
    const int* __restrict__ perm_src, const float* __restrict__ b2,
    float* __restrict__ out, int Nn)
{
    int wid = (blockIdx.x * blockDim.x + threadIdx.x) >> 6;
    int lane = threadIdx.x & 63;
    if (wid >= Nn) return;
    const int beg = row_start[wid], end = row_start[wid + 1];
    const float er = er2[wid];
    const bool act = lane < NCLS;
    const int cl = act ? lane : 0;

    float acc = 0.f, denom = 0.f;
    for (int i0 = beg; i0 < end; i0 += 64) {
        int cnt = min(end - i0, 64);
        int pv = (i0 + lane < end) ? perm_src[i0 + lane] : 0;
        int j = 0;
        for (; j + 4 <= cnt; j += 4) {
            int s0 = __shfl(pv, j), s1 = __shfl(pv, j + 1);
            int s2 = __shfl(pv, j + 2), s3 = __shfl(pv, j + 3);
            float e0 = el2[s0] + er, e1 = el2[s1] + er;
            float e2 = el2[s2] + er, e3 = el2[s3] + er;
            ushort r0 = h2b[(size_t)s0 * NCLS + cl];
            ushort r1 = h2b[(size_t)s1 * NCLS + cl];
            ushort r2 = h2b[(size_t)s2 * NCLS + cl];
            ushort r3 = h2b[(size_t)s3 * NCLS + cl];
            e0 = (e0 >= 0.f) ? e0 : 0.2f * e0;
            e1 = (e1 >= 0.f) ? e1 : 0.2f * e1;
            e2 = (e2 >= 0.f) ? e2 : 0.2f * e2;
            e3 = (e3 >= 0.f) ? e3 : 0.2f * e3;
            float w0 = __expf(fminf(e0, 80.f)), w1 = __expf(fminf(e1, 80.f));
            float w2 = __expf(fminf(e2, 80.f)), w3 = __expf(fminf(e3, 80.f));
            denom += (w0 + w1) + (w2 + w3);
            acc += bf2f(r0) * w0 + bf2f(r1) * w1 + bf2f(r2) * w2 + bf2f(r3) * w3;
        }
        for (; j < cnt; j++) {
            int s = __shfl(pv, j);
            float e = el2[s] + er;
            e = (e >= 0.f) ? e : 0.2f * e;
            float w = __expf(fminf(e, 80.f));
            denom += w;
            acc += bf2f(h2b[(size_t)s * NCLS + cl]) * w;
        }
    }
    float v = act ? (acc / (denom + 1e-9f) + b2[lane]) : -1e30f;

    float mx = v;
#pragma unroll
    for (int o = 1; o < 64; o <<= 1) mx = fmaxf(mx, __shfl_xor(mx, o));
    float sx = act ? __expf(v - mx) : 0.f;
#pragma unroll
    for (int o = 1; o < 64; o <<= 1) sx += __shfl_xor(sx, o);
    if (act) out[(size_t)wid * NCLS + lane] = v - mx - __logf(sx);
}

// ---------------------------------------------------------------------------
extern "C" void kernel_launch(void* const* d_in, const int* in_sizes, int n_in,
                              void* d_out, int out_size, void* d_ws, size_t ws_size,
                              hipStream_t stream)
{
    const float* x   = (const float*)d_in[0];
    const int*   src = (const int*)d_in[1];
    const int*   dst = (const int*)d_in[2];
    const float* W1  = (const float*)d_in[3];
    const float* al1 = (const float*)d_in[4];
    const float* ar1 = (const float*)d_in[5];
    const float* b1  = (const float*)d_in[6];
    const float* W2  = (const float*)d_in[7];
    const float* al2 = (const float*)d_in[8];
    const float* ar2 = (const float*)d_in[9];
    const float* b2  = (const float*)d_in[10];
    float* out = (float*)d_out;

    const int Nn = in_sizes[0] / 512;
    const int Ee = in_sizes[1];
    const int nBuckets = (Nn + BW - 1) / BW;

    // workspace layout
    ushort* h1b   = (ushort*)d_ws;                 // N*64
    ushort* hmidb = h1b + (size_t)Nn * 64;         // N*64
    ushort* h2b   = hmidb + (size_t)Nn * 64;       // N*40
    ushort* W1t   = h2b + (size_t)Nn * NCLS;       // 64*512
    float* el1  = (float*)(W1t + 64 * 512);        // N*8
    float* er1  = el1 + (size_t)Nn * 8;
    float* el2  = er1 + (size_t)Nn * 8;            // N
    float* er2  = el2 + Nn;
    float* wal2 = er2 + Nn;                        // 64
    float* war2 = wal2 + 64;                       // 64
    int* counts    = (int*)(war2 + 64);            // N
    int* row_start = counts + Nn;                  // N+1
    int* row_cur   = row_start + Nn + 1;           // N
    int* blockOffs = row_cur + Nn;                 // 512
    int* bcur      = blockOffs + 512;              // nBuckets (+pad)
    int* perm_src  = bcur + ((nBuckets + 255) & ~255); // E
    unsigned* packed = (unsigned*)(perm_src + Ee); // E

    const int nb = (Nn + 255) / 256;

    // CSR build
    hipMemsetAsync(counts, 0, (size_t)Nn * sizeof(int), stream);
    count_kernel<<<(Ee + 255) / 256, 256, 0, stream>>>(dst, counts, Ee);
    scan1_kernel<<<nb, 256, 0, stream>>>(counts, row_start, blockOffs, Nn);
    scan2_kernel<<<1, 512, 0, stream>>>(blockOffs, nb);
    scan3_kernel<<<nb, 256, 0, stream>>>(row_start, blockOffs, row_cur, Nn, Ee);
    bcur_init_kernel<<<(nBuckets + 255) / 256, 256, 0, stream>>>(row_start, bcur, nBuckets);
    bucket_scatter_kernel<<<(Ee + 255) / 256, 256, 0, stream>>>(src, dst, bcur, packed, Ee);
    final_scatter_kernel<<<nBuckets, 256, 0, stream>>>(packed, row_start, row_cur, perm_src, Nn, Ee);

    // layer 1
    convW1_kernel<<<(512 * 64 + 255) / 256, 256, 0, stream>>>(W1, W1t);
    gemm1_mfma_kernel<<<(Nn + 63) / 64, 256, 0, stream>>>(x, W1t, h1b, Nn);
    elr1_kernel<<<(Nn * 8 + 255) / 256, 256, 0, stream>>>(h1b, al1, ar1, el1, er1, Nn);
    agg1_kernel<<<(Nn + 3) / 4, 256, 0, stream>>>(h1b, el1, er1, row_start, perm_src, b1, hmidb, Nn);

    // layer 2
    prep2_kernel<<<1, 64, 0, stream>>>(W2, al2, ar2, wal2, war2);
    gemm2_kernel<<<(Nn + 255) / 256, 256, 0, stream>>>(hmidb, W2, wal2, war2, h2b, el2, er2, Nn);
    agg2_kernel<<<(Nn + 3) / 4, 256, 0, stream>>>(h2b, el2, er2, row_start, perm_src, b2, out, Nn);
}

// Round 4
// 359.823 us; speedup vs baseline: 1.3767x; 1.3767x over previous
//
#include <hip/hip_runtime.h>
#include <hip/hip_bf16.h>
#include <math.h>

#define NCLS 40
#define PWG 256        // partition workgroups
#define BSH 9          // log2(nodes per bucket) = 512 nodes/bucket
#define NBMAX 512

typedef __attribute__((ext_vector_type(8))) short bf16x8;
typedef __attribute__((ext_vector_type(4))) float f32x4;

__device__ inline float bf2f(ushort u) {
    unsigned v = ((unsigned)u) << 16;
    float f;
    __builtin_memcpy(&f, &v, 4);
    return f;
}
__device__ inline ushort f2bf(float f) {
    unsigned v;
    __builtin_memcpy(&v, &f, 4);
    unsigned r = (v + 0x7FFFu + ((v >> 16) & 1u)) >> 16;
    return (ushort)r;
}

// ---------------------------------------------------------------------------
// convW1: W1 [512][64] fp32 -> W1t [64][512] bf16 (transposed)
// ---------------------------------------------------------------------------
__global__ __launch_bounds__(256) void convW1_kernel(const float* __restrict__ W1,
                                                     ushort* __restrict__ W1t)
{
    int id = blockIdx.x * 256 + threadIdx.x;  // 32768
    if (id >= 512 * 64) return;
    int k = id >> 6, c = id & 63;
    W1t[c * 512 + k] = f2bf(W1[k * 64 + c]);
}

// ---------------------------------------------------------------------------
// GEMM1 (MFMA): h1b = bf16(x) @ bf16(W1). 64-row tile, 256 thr = 4 waves.
// ---------------------------------------------------------------------------
__global__ __launch_bounds__(256) void gemm1_mfma_kernel(
    const float* __restrict__ x, const ushort* __restrict__ W1t,
    ushort* __restrict__ h1b, int Nn)
{
    __shared__ ushort As[64 * 40];
    __shared__ ushort Bs[64 * 40];
    const int t = threadIdx.x;
    const int lane = t & 63, w = t >> 6;
    const int tile = blockIdx.x * 64;

    f32x4 acc[4] = {};

    const int sr = t >> 2;
    const int sk = (t & 3) * 8;
    const int arow = tile + sr;
    const bool rowok = arow < Nn;
    const float* xrow = x + (size_t)arow * 512;
    const ushort* wrow = W1t + (size_t)sr * 512;

    const int r = lane & 15, g = lane >> 4;

    for (int k0 = 0; k0 < 512; k0 += 32) {
        float4 f0, f1;
        if (rowok) {
            f0 = *(const float4*)(xrow + k0 + sk);
            f1 = *(const float4*)(xrow + k0 + sk + 4);
        } else {
            f0 = make_float4(0.f, 0.f, 0.f, 0.f);
            f1 = f0;
        }
        ushort* ap = &As[sr * 40 + sk];
        ap[0] = f2bf(f0.x); ap[1] = f2bf(f0.y); ap[2] = f2bf(f0.z); ap[3] = f2bf(f0.w);
        ap[4] = f2bf(f1.x); ap[5] = f2bf(f1.y); ap[6] = f2bf(f1.z); ap[7] = f2bf(f1.w);
        *(bf16x8*)&Bs[sr * 40 + sk] = *(const bf16x8*)(wrow + k0 + sk);
        __syncthreads();

        bf16x8 afrag = *(const bf16x8*)&As[(w * 16 + r) * 40 + g * 8];
#pragma unroll
        for (int cb = 0; cb < 4; cb++) {
            bf16x8 bfrag = *(const bf16x8*)&Bs[(cb * 16 + r) * 40 + g * 8];
            acc[cb] = __builtin_amdgcn_mfma_f32_16x16x32_bf16(afrag, bfrag, acc[cb], 0, 0, 0);
        }
        __syncthreads();
    }

#pragma unroll
    for (int cb = 0; cb < 4; cb++) {
#pragma unroll
        for (int v = 0; v < 4; v++) {
            int row = tile + w * 16 + g * 4 + v;
            if (row < Nn) h1b[(size_t)row * 64 + cb * 16 + r] = f2bf(acc[cb][v]);
        }
    }
}

// ---------------------------------------------------------------------------
// elr1: el1[n,h] = sum_d h1[n,h,d]*al1[h,d]; er1 likewise. thread = n*8+h.
// ---------------------------------------------------------------------------
__global__ __launch_bounds__(256) void elr1_kernel(
    const ushort* __restrict__ h1b, const float* __restrict__ al1,
    const float* __restrict__ ar1, float* __restrict__ el1,
    float* __restrict__ er1, int Nn)
{
    int id = blockIdx.x * 256 + threadIdx.x;
    if (id >= Nn * 8) return;
    int h = id & 7;
    const ushort* p = h1b + (size_t)id * 8;
    ushort4 u0 = *(const ushort4*)p;
    ushort4 u1 = *(const ushort4*)(p + 4);
    float v0 = bf2f(u0.x), v1 = bf2f(u0.y), v2 = bf2f(u0.z), v3 = bf2f(u0.w);
    float v4 = bf2f(u1.x), v5 = bf2f(u1.y), v6 = bf2f(u1.z), v7 = bf2f(u1.w);
    const float* a = al1 + h * 8;
    const float* b = ar1 + h * 8;
    el1[id] = v0 * a[0] + v1 * a[1] + v2 * a[2] + v3 * a[3] + v4 * a[4] + v5 * a[5] + v6 * a[6] + v7 * a[7];
    er1[id] = v0 * b[0] + v1 * b[1] + v2 * b[2] + v3 * b[3] + v4 * b[4] + v5 * b[5] + v6 * b[6] + v7 * b[7];
}

// ---------------------------------------------------------------------------
// CSR build via radix partition over 512-node buckets.
// A) hist: per-WG LDS histogram -> hist[bucket*PWG + wg]
// ---------------------------------------------------------------------------
__global__ __launch_bounds__(256) void hist_kernel(const int* __restrict__ dst,
                                                   int* __restrict__ hist,
                                                   int Ee, int chunk, int NB)
{
    __shared__ int lh[NBMAX];
    const int wg = blockIdx.x, tid = threadIdx.x;
    for (int i = tid; i < NB; i += 256) lh[i] = 0;
    __syncthreads();
    const int beg = wg * chunk;
    const int endv = min(Ee, beg + chunk);
    for (int i = beg + tid; i < endv; i += 256) atomicAdd(&lh[dst[i] >> BSH], 1);
    __syncthreads();
    for (int b = tid; b < NB; b += 256) hist[b * PWG + wg] = lh[b];
}

// ---------------------------------------------------------------------------
// B) exclusive scan of hist (bucket-major, length NB*PWG), single WG.
//    Also emits bucketBase[b] = hist[b*PWG] (post-scan) and bucketBase[NB]=E.
// ---------------------------------------------------------------------------
__global__ __launch_bounds__(1024) void scanhist_kernel(int* __restrict__ hist,
                                                        int total,
                                                        int* __restrict__ bucketBase,
                                                        int NB, int Ee)
{
    __shared__ int s[1024];
    const int tid = threadIdx.x;
    int running = 0;
    for (int t0 = 0; t0 < total; t0 += 1024) {
        int i = t0 + tid;
        int v = (i < total) ? hist[i] : 0;
        s[tid] = v;
        __syncthreads();
#pragma unroll
        for (int o = 1; o < 1024; o <<= 1) {
            int t = (tid >= o) ? s[tid - o] : 0;
            __syncthreads();
            s[tid] += t;
            __syncthreads();
        }
        if (i < total) hist[i] = running + s[tid] - v;
        int tt = s[1023];
        __syncthreads();
        running += tt;
    }
    __syncthreads();
    for (int b = tid; b < NB; b += 1024) bucketBase[b] = hist[b * PWG];
    if (tid == 0) bucketBase[NB] = Ee;
}

// ---------------------------------------------------------------------------
// C) partition: each WG scatters its edges into its private per-bucket
//    sub-regions (LDS cursors, zero global atomics).
// ---------------------------------------------------------------------------
__global__ __launch_bounds__(256) void partition_kernel(const int* __restrict__ src,
                                                        const int* __restrict__ dst,
                                                        const int* __restrict__ hist,
                                                        int2* __restrict__ ebuf,
                                                        int Ee, int chunk, int NB)
{
    __shared__ int cur[NBMAX];
    const int wg = blockIdx.x, tid = threadIdx.x;
    for (int b = tid; b < NB; b += 256) cur[b] = hist[b * PWG + wg];
    __syncthreads();
    const int beg = wg * chunk;
    const int endv = min(Ee, beg + chunk);
    for (int i = beg + tid; i < endv; i += 256) {
        int d = dst[i];
        int p = atomicAdd(&cur[d >> BSH], 1);
        int2 e;
        e.x = src[i];
        e.y = d;
        ebuf[p] = e;
    }
}

// ---------------------------------------------------------------------------
// D) per-bucket CSR: LDS node histogram -> LDS scan -> row_start (coalesced)
//    + perm_src scatter confined to the bucket's own contiguous window.
// ---------------------------------------------------------------------------
__global__ __launch_bounds__(512) void bucket_csr_kernel(const int2* __restrict__ ebuf,
                                                         const int* __restrict__ bucketBase,
                                                         int* __restrict__ row_start,
                                                         int* __restrict__ perm_src,
                                                         int Nn, int Ee, int NB)
{
    __shared__ int cnt[512];
    __shared__ int s[512];
    __shared__ int cur[512];
    const int b = blockIdx.x, tid = threadIdx.x;
    const int base = b << BSH;
    const int bb = bucketBase[b], be = bucketBase[b + 1];

    cnt[tid] = 0;
    __syncthreads();
    for (int i = bb + tid; i < be; i += 512) {
        int2 e = ebuf[i];
        atomicAdd(&cnt[e.y - base], 1);
    }
    __syncthreads();
    int v = cnt[tid];
    s[tid] = v;
    __syncthreads();
#pragma unroll
    for (int o = 1; o < 512; o <<= 1) {
        int t = (tid >= o) ? s[tid - o] : 0;
        __syncthreads();
        s[tid] += t;
        __syncthreads();
    }
    const int off = bb + s[tid] - v;
    const int node = base + tid;
    if (node < Nn) row_start[node] = off;
    cur[tid] = off;
    __syncthreads();
    for (int i = bb + tid; i < be; i += 512) {
        int2 e = ebuf[i];
        int p = atomicAdd(&cur[e.y - base], 1);
        perm_src[p] = e.x;
    }
    if (b == NB - 1 && tid == 0) row_start[Nn] = Ee;
}

// ---------------------------------------------------------------------------
// agg1: one wave per dst node, lane = h*8+d. Single pass (no max; |e| small).
// ---------------------------------------------------------------------------
__global__ __launch_bounds__(256) void agg1_kernel(
    const ushort* __restrict__ h1b, const float* __restrict__ el1,
    const float* __restrict__ er1, const int* __restrict__ row_start,
    const int* __restrict__ perm_src, const float* __restrict__ b1,
    ushort* __restrict__ hmidb, int Nn)
{
    int wid = (blockIdx.x * blockDim.x + threadIdx.x) >> 6;
    int lane = threadIdx.x & 63;
    if (wid >= Nn) return;
    const int h = lane >> 3;
    const int beg = row_start[wid], end = row_start[wid + 1];
    const float er = er1[wid * 8 + h];

    float acc = 0.f, denom = 0.f;
    for (int i0 = beg; i0 < end; i0 += 64) {
        int cnt = min(end - i0, 64);
        int pv = (i0 + lane < end) ? perm_src[i0 + lane] : 0;
        int j = 0;
        for (; j + 4 <= cnt; j += 4) {
            int s0 = __shfl(pv, j), s1 = __shfl(pv, j + 1);
            int s2 = __shfl(pv, j + 2), s3 = __shfl(pv, j + 3);
            float e0 = el1[s0 * 8 + h] + er;
            float e1 = el1[s1 * 8 + h] + er;
            float e2 = el1[s2 * 8 + h] + er;
            float e3 = el1[s3 * 8 + h] + er;
            ushort r0 = h1b[(size_t)s0 * 64 + lane];
            ushort r1 = h1b[(size_t)s1 * 64 + lane];
            ushort r2 = h1b[(size_t)s2 * 64 + lane];
            ushort r3 = h1b[(size_t)s3 * 64 + lane];
            e0 = (e0 >= 0.f) ? e0 : 0.2f * e0;
            e1 = (e1 >= 0.f) ? e1 : 0.2f * e1;
            e2 = (e2 >= 0.f) ? e2 : 0.2f * e2;
            e3 = (e3 >= 0.f) ? e3 : 0.2f * e3;
            float w0 = __expf(fminf(e0, 80.f)), w1 = __expf(fminf(e1, 80.f));
            float w2 = __expf(fminf(e2, 80.f)), w3 = __expf(fminf(e3, 80.f));
            denom += (w0 + w1) + (w2 + w3);
            acc += bf2f(r0) * w0 + bf2f(r1) * w1 + bf2f(r2) * w2 + bf2f(r3) * w3;
        }
        for (; j < cnt; j++) {
            int s = __shfl(pv, j);
            float e = el1[s * 8 + h] + er;
            e = (e >= 0.f) ? e : 0.2f * e;
            float w = __expf(fminf(e, 80.f));
            denom += w;
            acc += bf2f(h1b[(size_t)s * 64 + lane]) * w;
        }
    }
    float v = acc / (denom + 1e-9f) + b1[lane];
    v = (v > 0.f) ? v : expm1f(v);  // ELU
    hmidb[(size_t)wid * 64 + lane] = f2bf(v);
}

// ---------------------------------------------------------------------------
// prep2: wal2[k] = sum_c W2[k][c]*al2[c]; war2 likewise
// ---------------------------------------------------------------------------
__global__ __launch_bounds__(64) void prep2_kernel(const float* __restrict__ W2,
                                                   const float* __restrict__ al2,
                                                   const float* __restrict__ ar2,
                                                   float* __restrict__ wal2,
                                                   float* __restrict__ war2)
{
    int k = threadIdx.x;  // 64
    float a = 0.f, b = 0.f;
    for (int c = 0; c < NCLS; c++) {
        float w = W2[k * NCLS + c];
        a += w * al2[c];
        b += w * ar2[c];
    }
    wal2[k] = a;
    war2[k] = b;
}

// ---------------------------------------------------------------------------
// GEMM2: h2b = hmid @ W2 (bf16 in, bf16 out) + el2/er2. One thread per node.
// ---------------------------------------------------------------------------
__global__ __launch_bounds__(256) void gemm2_kernel(
    const ushort* __restrict__ hmidb, const float* __restrict__ W2,
    const float* __restrict__ wal2, const float* __restrict__ war2,
    ushort* __restrict__ h2b, float* __restrict__ el2, float* __restrict__ er2,
    int Nn)
{
    __shared__ float w2s[64 * NCLS];
    __shared__ float wals[64], wars[64];
    for (int i = threadIdx.x; i < 64 * NCLS; i += blockDim.x) w2s[i] = W2[i];
    if (threadIdx.x < 64) {
        wals[threadIdx.x] = wal2[threadIdx.x];
        wars[threadIdx.x] = war2[threadIdx.x];
    }
    __syncthreads();
    int n = blockIdx.x * blockDim.x + threadIdx.x;
    if (n >= Nn) return;

    float out[NCLS];
#pragma unroll
    for (int c = 0; c < NCLS; c++) out[c] = 0.f;
    float accel = 0.f, accer = 0.f;

#pragma unroll 4
    for (int k4 = 0; k4 < 16; k4++) {
        ushort4 u = *(const ushort4*)&hmidb[(size_t)n * 64 + k4 * 4];
        float h0 = bf2f(u.x), h1 = bf2f(u.y), h2 = bf2f(u.z), h3 = bf2f(u.w);
        accel += h0 * wals[k4 * 4] + h1 * wals[k4 * 4 + 1] + h2 * wals[k4 * 4 + 2] + h3 * wals[k4 * 4 + 3];
        accer += h0 * wars[k4 * 4] + h1 * wars[k4 * 4 + 1] + h2 * wars[k4 * 4 + 2] + h3 * wars[k4 * 4 + 3];
#pragma unroll
        for (int c = 0; c < NCLS; c++) {
            out[c] += h0 * w2s[(k4 * 4 + 0) * NCLS + c] + h1 * w2s[(k4 * 4 + 1) * NCLS + c] +
                      h2 * w2s[(k4 * 4 + 2) * NCLS + c] + h3 * w2s[(k4 * 4 + 3) * NCLS + c];
        }
    }
    el2[n] = accel;
    er2[n] = accer;
#pragma unroll
    for (int c = 0; c < NCLS; c++) h2b[(size_t)n * NCLS + c] = f2bf(out[c]);
}

// ---------------------------------------------------------------------------
// agg2 + log_softmax: one wave per dst node; lane = class. Single pass.
// ---------------------------------------------------------------------------
__global__ __launch_bounds__(256) void agg2_kernel(
    const ushort* __restrict__ h2b, const float* __restrict__ el2,
    const float* __restrict__ er2, const int* __restrict__ row_start,
    const int* __restrict__ perm_src, const float* __restrict__ b2,
    float* __restrict__ out, int Nn)
{
    int wid = (blockIdx.x * blockDim.x + threadIdx.x) >> 6;
    int lane = threadIdx.x & 63;
    if (wid >= Nn) return;
    const int beg = row_start[wid], end = row_start[wid + 1];
    const float er = er2[wid];
    const bool act = lane < NCLS;
    const int cl = act ? lane : 0;

    float acc = 0.f, denom = 0.f;
    for (int i0 = beg; i0 < end; i0 += 64) {
        int cnt = min(end - i0, 64);
        int pv = (i0 + lane < end) ? perm_src[i0 + lane] : 0;
        int j = 0;
        for (; j + 4 <= cnt; j += 4) {
            int s0 = __shfl(pv, j), s1 = __shfl(pv, j + 1);
            int s2 = __shfl(pv, j + 2), s3 = __shfl(pv, j + 3);
            float e0 = el2[s0] + er, e1 = el2[s1] + er;
            float e2 = el2[s2] + er, e3 = el2[s3] + er;
            ushort r0 = h2b[(size_t)s0 * NCLS + cl];
            ushort r1 = h2b[(size_t)s1 * NCLS + cl];
            ushort r2 = h2b[(size_t)s2 * NCLS + cl];
            ushort r3 = h2b[(size_t)s3 * NCLS + cl];
            e0 = (e0 >= 0.f) ? e0 : 0.2f * e0;
            e1 = (e1 >= 0.f) ? e1 : 0.2f * e1;
            e2 = (e2 >= 0.f) ? e2 : 0.2f * e2;
            e3 = (e3 >= 0.f) ? e3 : 0.2f * e3;
            float w0 = __expf(fminf(e0, 80.f)), w1 = __expf(fminf(e1, 80.f));
            float w2 = __expf(fminf(e2, 80.f)), w3 = __expf(fminf(e3, 80.f));
            denom += (w0 + w1) + (w2 + w3);
            acc += bf2f(r0) * w0 + bf2f(r1) * w1 + bf2f(r2) * w2 + bf2f(r3) * w3;
        }
        for (; j < cnt; j++) {
            int s = __shfl(pv, j);
            float e = el2[s] + er;
            e = (e >= 0.f) ? e : 0.2f * e;
            float w = __expf(fminf(e, 80.f));
            denom += w;
            acc += bf2f(h2b[(size_t)s * NCLS + cl]) * w;
        }
    }
    float v = act ? (acc / (denom + 1e-9f) + b2[lane]) : -1e30f;

    float mx = v;
#pragma unroll
    for (int o = 1; o < 64; o <<= 1) mx = fmaxf(mx, __shfl_xor(mx, o));
    float sx = act ? __expf(v - mx) : 0.f;
#pragma unroll
    for (int o = 1; o < 64; o <<= 1) sx += __shfl_xor(sx, o);
    if (act) out[(size_t)wid * NCLS + lane] = v - mx - __logf(sx);
}

// ---------------------------------------------------------------------------
extern "C" void kernel_launch(void* const* d_in, const int* in_sizes, int n_in,
                              void* d_out, int out_size, void* d_ws, size_t ws_size,
                              hipStream_t stream)
{
    const float* x   = (const float*)d_in[0];
    const int*   src = (const int*)d_in[1];
    const int*   dst = (const int*)d_in[2];
    const float* W1  = (const float*)d_in[3];
    const float* al1 = (const float*)d_in[4];
    const float* ar1 = (const float*)d_in[5];
    const float* b1  = (const float*)d_in[6];
    const float* W2  = (const float*)d_in[7];
    const float* al2 = (const float*)d_in[8];
    const float* ar2 = (const float*)d_in[9];
    const float* b2  = (const float*)d_in[10];
    float* out = (float*)d_out;

    const int Nn = in_sizes[0] / 512;
    const int Ee = in_sizes[1];
    const int NB = (Nn + (1 << BSH) - 1) >> BSH;   // buckets of 512 nodes
    const int chunk = (Ee + PWG - 1) / PWG;

    // workspace layout (16B-aligned bump allocator)
    char* wsb = (char*)d_ws;
    size_t off = 0;
    auto alloc = [&](size_t bytes) -> void* {
        off = (off + 15) & ~(size_t)15;
        void* p = wsb + off;
        off += bytes;
        return p;
    };
    ushort* h1b   = (ushort*)alloc((size_t)Nn * 64 * 2);
    ushort* hmidb = (ushort*)alloc((size_t)Nn * 64 * 2);
    ushort* h2b   = (ushort*)alloc((size_t)Nn * NCLS * 2);
    ushort* W1t   = (ushort*)alloc(64 * 512 * 2);
    float* el1  = (float*)alloc((size_t)Nn * 8 * 4);
    float* er1  = (float*)alloc((size_t)Nn * 8 * 4);
    float* el2  = (float*)alloc((size_t)Nn * 4);
    float* er2  = (float*)alloc((size_t)Nn * 4);
    float* wal2 = (float*)alloc(64 * 4);
    float* war2 = (float*)alloc(64 * 4);
    int* row_start  = (int*)alloc((size_t)(Nn + 1) * 4);
    int* hist       = (int*)alloc((size_t)NB * PWG * 4);
    int* bucketBase = (int*)alloc((size_t)(NB + 1) * 4);
    int* perm_src   = (int*)alloc((size_t)Ee * 4);
    int2* ebuf      = (int2*)alloc((size_t)Ee * 8);

    // CSR build (radix partition, no global atomics)
    hist_kernel<<<PWG, 256, 0, stream>>>(dst, hist, Ee, chunk, NB);
    scanhist_kernel<<<1, 1024, 0, stream>>>(hist, NB * PWG, bucketBase, NB, Ee);
    partition_kernel<<<PWG, 256, 0, stream>>>(src, dst, hist, ebuf, Ee, chunk, NB);
    bucket_csr_kernel<<<NB, 512, 0, stream>>>(ebuf, bucketBase, row_start, perm_src, Nn, Ee, NB);

    // layer 1
    convW1_kernel<<<(512 * 64 + 255) / 256, 256, 0, stream>>>(W1, W1t);
    gemm1_mfma_kernel<<<(Nn + 63) / 64, 256, 0, stream>>>(x, W1t, h1b, Nn);
    elr1_kernel<<<(Nn * 8 + 255) / 256, 256, 0, stream>>>(h1b, al1, ar1, el1, er1, Nn);
    agg1_kernel<<<(Nn + 3) / 4, 256, 0, stream>>>(h1b, el1, er1, row_start, perm_src, b1, hmidb, Nn);

    // layer 2
    prep2_kernel<<<1, 64, 0, stream>>>(W2, al2, ar2, wal2, war2);
    gemm2_kernel<<<(Nn + 255) / 256, 256, 0, stream>>>(hmidb, W2, wal2, war2, h2b, el2, er2, Nn);
    agg2_kernel<<<(Nn + 3) / 4, 256, 0, stream>>>(h2b, el2, er2, row_start, perm_src, b2, out, Nn);
}

// Round 5
// 265.370 us; speedup vs baseline: 1.8667x; 1.3559x over previous
//
#include <hip/hip_runtime.h>
#include <hip/hip_bf16.h>
#include <math.h>

#define NCLS 40
#define PWG 256        // partition workgroups
#define BSH 9          // log2(nodes per bucket) = 512 nodes/bucket
#define NBMAX 512
#define SRCB 23        // src packed in low 23 bits, local node id in high 9
#define CSRCAP 14336   // staged edges per bucket (56 KB LDS)

typedef __attribute__((ext_vector_type(8))) short bf16x8;
typedef __attribute__((ext_vector_type(4))) float f32x4;

__device__ inline float bf2f(ushort u) {
    unsigned v = ((unsigned)u) << 16;
    float f;
    __builtin_memcpy(&f, &v, 4);
    return f;
}
__device__ inline ushort f2bf(float f) {
    unsigned v;
    __builtin_memcpy(&v, &f, 4);
    unsigned r = (v + 0x7FFFu + ((v >> 16) & 1u)) >> 16;
    return (ushort)r;
}

// ---------------------------------------------------------------------------
// conv_prep: blocks 0..127 transpose W1 -> bf16 W1t[64][512];
//            block 128 computes wal2/war2 (W2 @ al2 / ar2).
// ---------------------------------------------------------------------------
__global__ __launch_bounds__(256) void conv_prep_kernel(
    const float* __restrict__ W1, ushort* __restrict__ W1t,
    const float* __restrict__ W2, const float* __restrict__ al2,
    const float* __restrict__ ar2, float* __restrict__ wal2,
    float* __restrict__ war2)
{
    if (blockIdx.x < 128) {
        int id = blockIdx.x * 256 + threadIdx.x;  // 32768
        int k = id >> 6, c = id & 63;
        W1t[c * 512 + k] = f2bf(W1[k * 64 + c]);
    } else {
        int k = threadIdx.x;
        if (k < 64) {
            float a = 0.f, b = 0.f;
            for (int c = 0; c < NCLS; c++) {
                float w = W2[k * NCLS + c];
                a += w * al2[c];
                b += w * ar2[c];
            }
            wal2[k] = a;
            war2[k] = b;
        }
    }
}

// ---------------------------------------------------------------------------
// GEMM1 (MFMA, reg-pipelined): h1b = bf16(x) @ bf16(W1).
// ---------------------------------------------------------------------------
__global__ __launch_bounds__(256) void gemm1_mfma_kernel(
    const float* __restrict__ x, const ushort* __restrict__ W1t,
    ushort* __restrict__ h1b, int Nn)
{
    __shared__ ushort As[64 * 40];
    __shared__ ushort Bs[64 * 40];
    const int t = threadIdx.x;
    const int lane = t & 63, w = t >> 6;
    const int tile = blockIdx.x * 64;

    f32x4 acc[4] = {};

    const int sr = t >> 2;
    const int sk = (t & 3) * 8;
    const int arow = tile + sr;
    const bool rowok = arow < Nn;
    const float* xrow = x + (size_t)arow * 512;
    const ushort* wrow = W1t + (size_t)sr * 512;

    const int r = lane & 15, g = lane >> 4;

    // prologue: load tile k0=0 into regs
    float4 f0, f1;
    bf16x8 bv;
    if (rowok) {
        f0 = *(const float4*)(xrow + sk);
        f1 = *(const float4*)(xrow + sk + 4);
    } else {
        f0 = make_float4(0.f, 0.f, 0.f, 0.f);
        f1 = f0;
    }
    bv = *(const bf16x8*)(wrow + sk);

    for (int k0 = 0; k0 < 512; k0 += 32) {
        // stage regs -> LDS (A converted to bf16, single b128 store each)
        bf16x8 av;
        av[0] = (short)f2bf(f0.x); av[1] = (short)f2bf(f0.y);
        av[2] = (short)f2bf(f0.z); av[3] = (short)f2bf(f0.w);
        av[4] = (short)f2bf(f1.x); av[5] = (short)f2bf(f1.y);
        av[6] = (short)f2bf(f1.z); av[7] = (short)f2bf(f1.w);
        *(bf16x8*)&As[sr * 40 + sk] = av;
        *(bf16x8*)&Bs[sr * 40 + sk] = bv;
        __syncthreads();

        // issue next tile's global loads (overlap with MFMA below)
        int k1 = k0 + 32;
        if (k1 < 512) {
            if (rowok) {
                f0 = *(const float4*)(xrow + k1 + sk);
                f1 = *(const float4*)(xrow + k1 + sk + 4);
            }
            bv = *(const bf16x8*)(wrow + k1 + sk);
        }

        bf16x8 afrag = *(const bf16x8*)&As[(w * 16 + r) * 40 + g * 8];
#pragma unroll
        for (int cb = 0; cb < 4; cb++) {
            bf16x8 bfrag = *(const bf16x8*)&Bs[(cb * 16 + r) * 40 + g * 8];
            acc[cb] = __builtin_amdgcn_mfma_f32_16x16x32_bf16(afrag, bfrag, acc[cb], 0, 0, 0);
        }
        __syncthreads();
    }

#pragma unroll
    for (int cb = 0; cb < 4; cb++) {
#pragma unroll
        for (int v = 0; v < 4; v++) {
            int row = tile + w * 16 + g * 4 + v;
            if (row < Nn) h1b[(size_t)row * 64 + cb * 16 + r] = f2bf(acc[cb][v]);
        }
    }
}

// ---------------------------------------------------------------------------
// elr1: el1[n,h] = sum_d h1[n,h,d]*al1[h,d]; er1 likewise. thread = n*8+h.
// ---------------------------------------------------------------------------
__global__ __launch_bounds__(256) void elr1_kernel(
    const ushort* __restrict__ h1b, const float* __restrict__ al1,
    const float* __restrict__ ar1, float* __restrict__ el1,
    float* __restrict__ er1, int Nn)
{
    int id = blockIdx.x * 256 + threadIdx.x;
    if (id >= Nn * 8) return;
    int h = id & 7;
    const ushort* p = h1b + (size_t)id * 8;
    ushort4 u0 = *(const ushort4*)p;
    ushort4 u1 = *(const ushort4*)(p + 4);
    float v0 = bf2f(u0.x), v1 = bf2f(u0.y), v2 = bf2f(u0.z), v3 = bf2f(u0.w);
    float v4 = bf2f(u1.x), v5 = bf2f(u1.y), v6 = bf2f(u1.z), v7 = bf2f(u1.w);
    const float* a = al1 + h * 8;
    const float* b = ar1 + h * 8;
    el1[id] = v0 * a[0] + v1 * a[1] + v2 * a[2] + v3 * a[3] + v4 * a[4] + v5 * a[5] + v6 * a[6] + v7 * a[7];
    er1[id] = v0 * b[0] + v1 * b[1] + v2 * b[2] + v3 * b[3] + v4 * b[4] + v5 * b[5] + v6 * b[6] + v7 * b[7];
}

// ---------------------------------------------------------------------------
// CSR build via radix partition over 512-node buckets.
// A) hist: per-WG LDS histogram -> hist[bucket*PWG + wg]
// ---------------------------------------------------------------------------
__global__ __launch_bounds__(256) void hist_kernel(const int* __restrict__ dst,
                                                   int* __restrict__ hist,
                                                   int Ee, int chunk, int NB)
{
    __shared__ int lh[NBMAX];
    const int wg = blockIdx.x, tid = threadIdx.x;
    for (int i = tid; i < NB; i += 256) lh[i] = 0;
    __syncthreads();
    const int beg = wg * chunk;
    const int endv = min(Ee, beg + chunk);
    for (int i = beg + tid; i < endv; i += 256) atomicAdd(&lh[dst[i] >> BSH], 1);
    __syncthreads();
    for (int b = tid; b < NB; b += 256) hist[b * PWG + wg] = lh[b];
}

// ---------------------------------------------------------------------------
// B1) scanA: per-bucket exclusive scan of its PWG-length row; total out.
// ---------------------------------------------------------------------------
__global__ __launch_bounds__(256) void scanA_kernel(int* __restrict__ hist,
                                                    int* __restrict__ bucketTot)
{
    __shared__ int s[256];
    const int b = blockIdx.x, tid = threadIdx.x;
    int v = hist[b * PWG + tid];
    s[tid] = v;
    __syncthreads();
#pragma unroll
    for (int o = 1; o < 256; o <<= 1) {
        int t = (tid >= o) ? s[tid - o] : 0;
        __syncthreads();
        s[tid] += t;
        __syncthreads();
    }
    hist[b * PWG + tid] = s[tid] - v;  // exclusive within bucket
    if (tid == 255) bucketTot[b] = s[255];
}

// ---------------------------------------------------------------------------
// B2) scanB: exclusive scan of bucket totals (NB <= 256) -> bucketBase.
// ---------------------------------------------------------------------------
__global__ __launch_bounds__(256) void scanB_kernel(const int* __restrict__ bucketTot,
                                                    int* __restrict__ bucketBase,
                                                    int NB, int Ee)
{
    __shared__ int s[256];
    const int tid = threadIdx.x;
    int v = (tid < NB) ? bucketTot[tid] : 0;
    s[tid] = v;
    __syncthreads();
#pragma unroll
    for (int o = 1; o < 256; o <<= 1) {
        int t = (tid >= o) ? s[tid - o] : 0;
        __syncthreads();
        s[tid] += t;
        __syncthreads();
    }
    if (tid < NB) bucketBase[tid] = s[tid] - v;
    if (tid == 0) bucketBase[NB] = Ee;
}

// ---------------------------------------------------------------------------
// C) partition: each WG scatters its edges (packed 4B) into its private
//    per-bucket sub-regions (LDS cursors, zero global atomics).
// ---------------------------------------------------------------------------
__global__ __launch_bounds__(256) void partition_kernel(const int* __restrict__ src,
                                                        const int* __restrict__ dst,
                                                        const int* __restrict__ hist,
                                                        const int* __restrict__ bucketBase,
                                                        unsigned* __restrict__ ebuf,
                                                        int Ee, int chunk, int NB)
{
    __shared__ int cur[NBMAX];
    const int wg = blockIdx.x, tid = threadIdx.x;
    for (int b = tid; b < NB; b += 256) cur[b] = hist[b * PWG + wg] + bucketBase[b];
    __syncthreads();
    const int beg = wg * chunk;
    const int endv = min(Ee, beg + chunk);
    for (int i = beg + tid; i < endv; i += 256) {
        int d = dst[i];
        int p = atomicAdd(&cur[d >> BSH], 1);
        ebuf[p] = ((unsigned)(d & ((1 << BSH) - 1)) << SRCB) | (unsigned)src[i];
    }
}

// ---------------------------------------------------------------------------
// D) per-bucket CSR: LDS-staged edges -> node histogram -> scan -> row_start
//    + perm_src scatter confined to the bucket's contiguous window.
// ---------------------------------------------------------------------------
__global__ __launch_bounds__(512) void bucket_csr_kernel(const unsigned* __restrict__ ebuf,
                                                         const int* __restrict__ bucketBase,
                                                         int* __restrict__ row_start,
                                                         int* __restrict__ perm_src,
                                                         int Nn, int Ee, int NB)
{
    __shared__ unsigned stage[CSRCAP];
    __shared__ int cnt[512];
    __shared__ int s[512];
    __shared__ int cur[512];
    const int b = blockIdx.x, tid = threadIdx.x;
    const int base = b << BSH;
    const int bb = bucketBase[b], be = bucketBase[b + 1];
    const int m = be - bb;

    cnt[tid] = 0;
    __syncthreads();
    for (int idx = tid; idx < m; idx += 512) {
        unsigned pk = ebuf[bb + idx];
        if (idx < CSRCAP) stage[idx] = pk;
        atomicAdd(&cnt[pk >> SRCB], 1);
    }
    __syncthreads();
    int v = cnt[tid];
    s[tid] = v;
    __syncthreads();
#pragma unroll
    for (int o = 1; o < 512; o <<= 1) {
        int t = (tid >= o) ? s[tid - o] : 0;
        __syncthreads();
        s[tid] += t;
        __syncthreads();
    }
    const int off = bb + s[tid] - v;
    const int node = base + tid;
    if (node < Nn) row_start[node] = off;
    cur[tid] = off;
    __syncthreads();
    for (int idx = tid; idx < m; idx += 512) {
        unsigned pk = (idx < CSRCAP) ? stage[idx] : ebuf[bb + idx];
        int p = atomicAdd(&cur[pk >> SRCB], 1);
        perm_src[p] = (int)(pk & ((1u << SRCB) - 1u));
    }
    if (b == NB - 1 && tid == 0) row_start[Nn] = Ee;
}

// ---------------------------------------------------------------------------
// agg1: one wave per dst node, lane = h*8+d. Single pass, 8-deep batches.
// ---------------------------------------------------------------------------
__global__ __launch_bounds__(256) void agg1_kernel(
    const ushort* __restrict__ h1b, const float* __restrict__ el1,
    const float* __restrict__ er1, const int* __restrict__ row_start,
    const int* __restrict__ perm_src, const float* __restrict__ b1,
    ushort* __restrict__ hmidb, int Nn)
{
    int wid = (blockIdx.x * blockDim.x + threadIdx.x) >> 6;
    int lane = threadIdx.x & 63;
    if (wid >= Nn) return;
    const int h = lane >> 3;
    const int beg = row_start[wid], end = row_start[wid + 1];
    const float er = er1[wid * 8 + h];

    float acc = 0.f, denom = 0.f;
    for (int i0 = beg; i0 < end; i0 += 64) {
        int cnt = min(end - i0, 64);
        int pv = (i0 + lane < end) ? perm_src[i0 + lane] : 0;
        int j = 0;
        for (; j + 8 <= cnt; j += 8) {
            int ss[8];
#pragma unroll
            for (int u = 0; u < 8; u++) ss[u] = __shfl(pv, j + u);
            float ev[8];
            ushort rv[8];
#pragma unroll
            for (int u = 0; u < 8; u++) ev[u] = el1[ss[u] * 8 + h];
#pragma unroll
            for (int u = 0; u < 8; u++) rv[u] = h1b[(size_t)ss[u] * 64 + lane];
#pragma unroll
            for (int u = 0; u < 8; u++) {
                float e = ev[u] + er;
                e = (e >= 0.f) ? e : 0.2f * e;
                float w = __expf(fminf(e, 80.f));
                denom += w;
                acc += bf2f(rv[u]) * w;
            }
        }
        for (; j + 4 <= cnt; j += 4) {
            int ss[4];
#pragma unroll
            for (int u = 0; u < 4; u++) ss[u] = __shfl(pv, j + u);
            float ev[4];
            ushort rv[4];
#pragma unroll
            for (int u = 0; u < 4; u++) ev[u] = el1[ss[u] * 8 + h];
#pragma unroll
            for (int u = 0; u < 4; u++) rv[u] = h1b[(size_t)ss[u] * 64 + lane];
#pragma unroll
            for (int u = 0; u < 4; u++) {
                float e = ev[u] + er;
                e = (e >= 0.f) ? e : 0.2f * e;
                float w = __expf(fminf(e, 80.f));
                denom += w;
                acc += bf2f(rv[u]) * w;
            }
        }
        for (; j < cnt; j++) {
            int sI = __shfl(pv, j);
            float e = el1[sI * 8 + h] + er;
            e = (e >= 0.f) ? e : 0.2f * e;
            float w = __expf(fminf(e, 80.f));
            denom += w;
            acc += bf2f(h1b[(size_t)sI * 64 + lane]) * w;
        }
    }
    float v = acc / (denom + 1e-9f) + b1[lane];
    v = (v > 0.f) ? v : expm1f(v);  // ELU
    hmidb[(size_t)wid * 64 + lane] = f2bf(v);
}

// ---------------------------------------------------------------------------
// GEMM2: h2b = hmid @ W2 (bf16 in, bf16 out) + el2/er2. One thread per node.
// ---------------------------------------------------------------------------
__global__ __launch_bounds__(256) void gemm2_kernel(
    const ushort* __restrict__ hmidb, const float* __restrict__ W2,
    const float* __restrict__ wal2, const float* __restrict__ war2,
    ushort* __restrict__ h2b, float* __restrict__ el2, float* __restrict__ er2,
    int Nn)
{
    __shared__ float w2s[64 * NCLS];
    __shared__ float wals[64], wars[64];
    for (int i = threadIdx.x; i < 64 * NCLS; i += blockDim.x) w2s[i] = W2[i];
    if (threadIdx.x < 64) {
        wals[threadIdx.x] = wal2[threadIdx.x];
        wars[threadIdx.x] = war2[threadIdx.x];
    }
    __syncthreads();
    int n = blockIdx.x * blockDim.x + threadIdx.x;
    if (n >= Nn) return;

    float out[NCLS];
#pragma unroll
    for (int c = 0; c < NCLS; c++) out[c] = 0.f;
    float accel = 0.f, accer = 0.f;

#pragma unroll 4
    for (int k4 = 0; k4 < 16; k4++) {
        ushort4 u = *(const ushort4*)&hmidb[(size_t)n * 64 + k4 * 4];
        float h0 = bf2f(u.x), h1 = bf2f(u.y), h2 = bf2f(u.z), h3 = bf2f(u.w);
        accel += h0 * wals[k4 * 4] + h1 * wals[k4 * 4 + 1] + h2 * wals[k4 * 4 + 2] + h3 * wals[k4 * 4 + 3];
        accer += h0 * wars[k4 * 4] + h1 * wars[k4 * 4 + 1] + h2 * wars[k4 * 4 + 2] + h3 * wars[k4 * 4 + 3];
#pragma unroll
        for (int c = 0; c < NCLS; c++) {
            out[c] += h0 * w2s[(k4 * 4 + 0) * NCLS + c] + h1 * w2s[(k4 * 4 + 1) * NCLS + c] +
                      h2 * w2s[(k4 * 4 + 2) * NCLS + c] + h3 * w2s[(k4 * 4 + 3) * NCLS + c];
        }
    }
    el2[n] = accel;
    er2[n] = accer;
#pragma unroll
    for (int c = 0; c < NCLS; c++) h2b[(size_t)n * NCLS + c] = f2bf(out[c]);
}

// ---------------------------------------------------------------------------
// agg2 + log_softmax: one wave per dst node; lane = class. 8-deep batches.
// ---------------------------------------------------------------------------
__global__ __launch_bounds__(256) void agg2_kernel(
    const ushort* __restrict__ h2b, const float* __restrict__ el2,
    const float* __restrict__ er2, const int* __restrict__ row_start,
    const int* __restrict__ perm_src, const float* __restrict__ b2,
    float* __restrict__ out, int Nn)
{
    int wid = (blockIdx.x * blockDim.x + threadIdx.x) >> 6;
    int lane = threadIdx.x & 63;
    if (wid >= Nn) return;
    const int beg = row_start[wid], end = row_start[wid + 1];
    const float er = er2[wid];
    const bool act = lane < NCLS;
    const int cl = act ? lane : 0;

    float acc = 0.f, denom = 0.f;
    for (int i0 = beg; i0 < end; i0 += 64) {
        int cnt = min(end - i0, 64);
        int pv = (i0 + lane < end) ? perm_src[i0 + lane] : 0;
        int j = 0;
        for (; j + 8 <= cnt; j += 8) {
            int ss[8];
#pragma unroll
            for (int u = 0; u < 8; u++) ss[u] = __shfl(pv, j + u);
            float ev[8];
            ushort rv[8];
#pragma unroll
            for (int u = 0; u < 8; u++) ev[u] = el2[ss[u]];
#pragma unroll
            for (int u = 0; u < 8; u++) rv[u] = h2b[(size_t)ss[u] * NCLS + cl];
#pragma unroll
            for (int u = 0; u < 8; u++) {
                float e = ev[u] + er;
                e = (e >= 0.f) ? e : 0.2f * e;
                float w = __expf(fminf(e, 80.f));
                denom += w;
                acc += bf2f(rv[u]) * w;
            }
        }
        for (; j + 4 <= cnt; j += 4) {
            int ss[4];
#pragma unroll
            for (int u = 0; u < 4; u++) ss[u] = __shfl(pv, j + u);
            float ev[4];
            ushort rv[4];
#pragma unroll
            for (int u = 0; u < 4; u++) ev[u] = el2[ss[u]];
#pragma unroll
            for (int u = 0; u < 4; u++) rv[u] = h2b[(size_t)ss[u] * NCLS + cl];
#pragma unroll
            for (int u = 0; u < 4; u++) {
                float e = ev[u] + er;
                e = (e >= 0.f) ? e : 0.2f * e;
                float w = __expf(fminf(e, 80.f));
                denom += w;
                acc += bf2f(rv[u]) * w;
            }
        }
        for (; j < cnt; j++) {
            int sI = __shfl(pv, j);
            float e = el2[sI] + er;
            e = (e >= 0.f) ? e : 0.2f * e;
            float w = __expf(fminf(e, 80.f));
            denom += w;
            acc += bf2f(h2b[(size_t)sI * NCLS + cl]) * w;
        }
    }
    float v = act ? (acc / (denom + 1e-9f) + b2[lane]) : -1e30f;

    float mx = v;
#pragma unroll
    for (int o = 1; o < 64; o <<= 1) mx = fmaxf(mx, __shfl_xor(mx, o));
    float sx = act ? __expf(v - mx) : 0.f;
#pragma unroll
    for (int o = 1; o < 64; o <<= 1) sx += __shfl_xor(sx, o);
    if (act) out[(size_t)wid * NCLS + lane] = v - mx - __logf(sx);
}

// ---------------------------------------------------------------------------
extern "C" void kernel_launch(void* const* d_in, const int* in_sizes, int n_in,
                              void* d_out, int out_size, void* d_ws, size_t ws_size,
                              hipStream_t stream)
{
    const float* x   = (const float*)d_in[0];
    const int*   src = (const int*)d_in[1];
    const int*   dst = (const int*)d_in[2];
    const float* W1  = (const float*)d_in[3];
    const float* al1 = (const float*)d_in[4];
    const float* ar1 = (const float*)d_in[5];
    const float* b1  = (const float*)d_in[6];
    const float* W2  = (const float*)d_in[7];
    const float* al2 = (const float*)d_in[8];
    const float* ar2 = (const float*)d_in[9];
    const float* b2  = (const float*)d_in[10];
    float* out = (float*)d_out;

    const int Nn = in_sizes[0] / 512;
    const int Ee = in_sizes[1];
    const int NB = (Nn + (1 << BSH) - 1) >> BSH;   // buckets of 512 nodes
    const int chunk = (Ee + PWG - 1) / PWG;

    // workspace layout (16B-aligned bump allocator)
    char* wsb = (char*)d_ws;
    size_t off = 0;
    auto alloc = [&](size_t bytes) -> void* {
        off = (off + 15) & ~(size_t)15;
        void* p = wsb + off;
        off += bytes;
        return p;
    };
    ushort* h1b   = (ushort*)alloc((size_t)Nn * 64 * 2);
    ushort* hmidb = (ushort*)alloc((size_t)Nn * 64 * 2);
    ushort* h2b   = (ushort*)alloc((size_t)Nn * NCLS * 2);
    ushort* W1t   = (ushort*)alloc(64 * 512 * 2);
    float* el1  = (float*)alloc((size_t)Nn * 8 * 4);
    float* er1  = (float*)alloc((size_t)Nn * 8 * 4);
    float* el2  = (float*)alloc((size_t)Nn * 4);
    float* er2  = (float*)alloc((size_t)Nn * 4);
    float* wal2 = (float*)alloc(64 * 4);
    float* war2 = (float*)alloc(64 * 4);
    int* row_start  = (int*)alloc((size_t)(Nn + 1) * 4);
    int* hist       = (int*)alloc((size_t)NB * PWG * 4);
    int* bucketTot  = (int*)alloc((size_t)NB * 4);
    int* bucketBase = (int*)alloc((size_t)(NB + 1) * 4);
    int* perm_src   = (int*)alloc((size_t)Ee * 4);
    unsigned* ebuf  = (unsigned*)alloc((size_t)Ee * 4);

    // CSR build (radix partition, no global atomics, hierarchical scan)
    hist_kernel<<<PWG, 256, 0, stream>>>(dst, hist, Ee, chunk, NB);
    scanA_kernel<<<NB, 256, 0, stream>>>(hist, bucketTot);
    scanB_kernel<<<1, 256, 0, stream>>>(bucketTot, bucketBase, NB, Ee);
    partition_kernel<<<PWG, 256, 0, stream>>>(src, dst, hist, bucketBase, ebuf, Ee, chunk, NB);
    bucket_csr_kernel<<<NB, 512, 0, stream>>>(ebuf, bucketBase, row_start, perm_src, Nn, Ee, NB);

    // layer 1
    conv_prep_kernel<<<129, 256, 0, stream>>>(W1, W1t, W2, al2, ar2, wal2, war2);
    gemm1_mfma_kernel<<<(Nn + 63) / 64, 256, 0, stream>>>(x, W1t, h1b, Nn);
    elr1_kernel<<<(Nn * 8 + 255) / 256, 256, 0, stream>>>(h1b, al1, ar1, el1, er1, Nn);
    agg1_kernel<<<(Nn + 3) / 4, 256, 0, stream>>>(h1b, el1, er1, row_start, perm_src, b1, hmidb, Nn);

    // layer 2
    gemm2_kernel<<<(Nn + 255) / 256, 256, 0, stream>>>(hmidb, W2, wal2, war2, h2b, el2, er2, Nn);
    agg2_kernel<<<(Nn + 3) / 4, 256, 0, stream>>>(h2b, el2, er2, row_start, perm_src, b2, out, Nn);
}